// Round 9
// baseline (2147.968 us; speedup 1.0000x reference)
//
#include <hip/hip_runtime.h>
#include <hip/hip_fp16.h>
#include <cmath>

#define BB 128
#define TT 365
#define DD 32
#define HH 512
#define G4H 2048  // 4*HH

// ws layout: buf0 fp16 at byte 0 (131072B used) | buf1 fp16 at byte 262144
//            (bar region at byte 524288 unused by v10; kept for fallback/cst)
//            cst at float-ofs 131328 (fallback only, fp32)
// hipMemsetAsync zeroes [0, 787456) bytes each call -> both h buffers all-zero
// (zero bits == tag 0 + h == 0, which is exactly step 0's expected state).

typedef float f32x4 __attribute__((ext_vector_type(4)));
typedef _Float16 f16x8 __attribute__((ext_vector_type(8)));

__device__ __forceinline__ float sigf(float z) { return 1.f / (1.f + __expf(-z)); }

// fast tanh: (1-e)/(1+e) with e=exp(-2|x|), sign restored; e<=1 so no overflow
__device__ __forceinline__ float ftanh(float z) {
  float a = fabsf(z);
  float e = __expf(-2.f * a);
  float r = (1.f - e) / (1.f + e);
  return (z < 0.f) ? -r : r;
}

// ---------------------------------------------------------------------------
// Persistent kernel v10: v8/v9's tiling (256 WGs x 512 thr, 16 batch groups
// x 8 rows x 16 col-WGs, W as MFMA B-fragments in VGPRs for 365 steps), but
// the cross-WG handshake is TAGGED DATA instead of counter barrier. v9's
// neutral result + counters showed the step is 4 serialized fabric RTs
// (store drain -> contended arrive-add -> count poll -> h load). v10: each
// 8B h-word (4 fp16) carries a 2-bit step tag (t mod 4) in the lsbs of
// fp16[0] (u64 bit0) and fp16[1] (bit16); consumers poll their own words
// until the tag matches. 2 RTs instead of 4; no arrive, no counter, no
// contention. Safety: 2 buffers x mod-4 tags -> stale (t-2) residue always
// mismatches; writer at step s polls all step-(s-1) words first, which
// data-depend on every WG's reads of the buffer being overwritten -> no
// lost windows. Op class unchanged: agent-scope __hip_atomic_load/store.
// Epilogue fully in-register: weight cols permuted so lane = {gate g, h-col
// j}: 3x shfl_xor gathers all 4 gates; c-state in VGPRs. ZxS/Cs/BiasS LDS
// and one syncthreads eliminated (3 -> 2 syncs/step).
// ---------------------------------------------------------------------------
__global__ __launch_bounds__(512, 2)
void lstm_persistent(const float* __restrict__ x,
                     const float* __restrict__ Wx,
                     const float* __restrict__ Wh,
                     const float* __restrict__ bias,
                     float* __restrict__ out,
                     float* __restrict__ hws) {
  __shared__ __align__(16) _Float16 WlH[128 * 552];  // 141312 B (init staging)
  __shared__ __align__(16) _Float16 AshH[8 * 552];   // 8832 B  [x(32)|h(512)]
  // total ~146.6 KB -> 1 WG/CU

  const int tid = threadIdx.x;
  const int lane = tid & 63;
  const int wv = tid >> 6;               // wave id [0,8)
  const int g = lane & 3;                // gate {i,f,g,o}
  const int hj_loc = (lane >> 2) & 3;    // h-col within wave's 4
  const int kq = lane >> 4;              // k-subgroup / C-row-quad [0,4)
  const int arow = lane & 15;            // A-fragment row (valid if <8)
  const int wg = blockIdx.x;
  const int bb = wg & 15;                // batch group [0,16), 8 rows
  const int nb = wg >> 4;                // col-WG [0,16), 32 h-cols
  const int b0g = bb * 8;
  const int n0 = nb * 32;

  // ---- stage weights as fp16 (layout: column = g*32 + hcol, k-major rows)
  {
    const int cl = tid & 31;
    const int pg = tid >> 5;  // [0,16)
    for (int it = 0; it < 136; ++it) {
      int p = it * 16 + pg;  // [0, 544*4)
      int k = p >> 2, gg = p & 3;
      int col = gg * HH + n0 + cl;
      float v = (k < DD) ? Wx[k * G4H + col] : Wh[(k - DD) * G4H + col];
      WlH[(gg * 32 + cl) * 552 + k] = (_Float16)v;
    }
  }

  _Float16* hb0 = (_Float16*)hws;  // fp16 h buffers (tagged words)
  _Float16* hb1 = (_Float16*)(hws + BB * HH);

  __syncthreads();  // WlH ready

  // ---- hoist this wave's B-fragments: lane covers (gate g, h-col wv*4+hj_loc)
  const int colidx = g * 32 + wv * 4 + hj_loc;  // column in WlH layout
  f16x8 bfrag[17];
#pragma unroll
  for (int kk = 0; kk < 17; ++kk)
    bfrag[kk] = *(const f16x8*)&WlH[colidx * 552 + kk * 32 + kq * 8];
  const float bias_r = bias[g * HH + n0 + wv * 4 + hj_loc];

  // ---- per-thread h-word addresses (2 words: idx = r*512+tid)
  const int rr0 = tid >> 7, kk0 = tid & 127;
  const int rr1 = (512 + tid) >> 7, kk1 = (512 + tid) & 127;

  // ---- c-state in registers (valid in lanes g==0, kq<2)
  float c_st[4] = {0.f, 0.f, 0.f, 0.f};

  // ---- stage x for t=0
  if (tid < 256) {
    int r = tid >> 5, c = tid & 31;
    AshH[r * 552 + c] = (_Float16)x[((size_t)(b0g + r) * TT + 0) * DD + c];
  }

  for (int t = 0; t < TT; ++t) {
    const _Float16* hprev = (t & 1) ? hb1 : hb0;
    _Float16* hnext = (t & 1) ? hb0 : hb1;

    // ---- tagged h loads: poll own words until tag == t&3 (agent-scope)
    {
      const unsigned exp_tag = (unsigned)t & 3u;
      const unsigned long long M = 0x10001ULL;
      const unsigned long long want =
          (unsigned long long)(exp_tag & 1u) |
          ((unsigned long long)((exp_tag >> 1) & 1u) << 16);
      const unsigned long long* a0 =
          (const unsigned long long*)(hprev + (size_t)(b0g + rr0) * HH + kk0 * 4);
      const unsigned long long* a1 =
          (const unsigned long long*)(hprev + (size_t)(b0g + rr1) * HH + kk1 * 4);
      unsigned long long w0 =
          __hip_atomic_load(a0, __ATOMIC_RELAXED, __HIP_MEMORY_SCOPE_AGENT);
      unsigned long long w1 =
          __hip_atomic_load(a1, __ATOMIC_RELAXED, __HIP_MEMORY_SCOPE_AGENT);
      while ((w0 & M) != want)
        w0 = __hip_atomic_load(a0, __ATOMIC_RELAXED, __HIP_MEMORY_SCOPE_AGENT);
      while ((w1 & M) != want)
        w1 = __hip_atomic_load(a1, __ATOMIC_RELAXED, __HIP_MEMORY_SCOPE_AGENT);
      *(unsigned long long*)&AshH[rr0 * 552 + DD + kk0 * 4] = w0;
      *(unsigned long long*)&AshH[rr1 * 552 + DD + kk1 * 4] = w1;
    }
    __syncthreads();  // (A) AshH ready (h now; x staged last iteration)

    // ---- MFMA: Z[16(8 valid) x 16] per wave, K=544, 2 accumulators
    f32x4 acc0 = {bias_r, bias_r, bias_r, bias_r};
    f32x4 acc1 = {0.f, 0.f, 0.f, 0.f};
#pragma unroll
    for (int kk = 0; kk < 17; ++kk) {
      f16x8 af;
      if (arow < 8) {
        af = *(const f16x8*)&AshH[arow * 552 + kk * 32 + kq * 8];
      } else {
        f16x8 z = {};
        af = z;
      }
      if (kk & 1)
        acc1 = __builtin_amdgcn_mfma_f32_16x16x32_f16(af, bfrag[kk], acc1, 0, 0, 0);
      else
        acc0 = __builtin_amdgcn_mfma_f32_16x16x32_f16(af, bfrag[kk], acc0, 0, 0, 0);
    }

    // ---- in-register epilogue. Lane holds z for (gate g, h-col, rows kq*4+r).
    float hv[4] = {0.f, 0.f, 0.f, 0.f};
#pragma unroll
    for (int r = 0; r < 4; ++r) {
      float z = acc0[r] + acc1[r];
      float x1 = __shfl_xor(z, 1);  // gate g^1
      float x2 = __shfl_xor(z, 2);  // gate g^2
      float x3 = __shfl_xor(z, 3);  // gate g^3
      if (g == 0 && kq < 2) {       // zi=z zf=x1 zg=x2 zo=x3
        float cnew = sigf(x1) * c_st[r] + sigf(z) * ftanh(x2);
        c_st[r] = cnew;
        hv[r] = sigf(x3) * ftanh(cnew);
      }
    }

    // ---- pack per row: h for wave's 4 h-cols gathered from lanes kq*16+{0,4,8,12}
    {
      const unsigned ntag = (unsigned)(t + 1) & 3u;
      const unsigned long long tagbits =
          (unsigned long long)(ntag & 1u) |
          ((unsigned long long)((ntag >> 1) & 1u) << 16);
      const int gbase = lane & 48;  // kq*16
#pragma unroll
      for (int r = 0; r < 4; ++r) {
        float b0 = __shfl(hv[r], gbase + 0);
        float b1 = __shfl(hv[r], gbase + 4);
        float b2 = __shfl(hv[r], gbase + 8);
        float b3 = __shfl(hv[r], gbase + 12);
        if (g == 0 && hj_loc == r && kq < 2) {
          int row = kq * 4 + r;           // reuse this lane for row kq*4+r
          int bg = b0g + row;
          int col = n0 + wv * 4;
          union { unsigned long long u; _Float16 h[4]; } pk;
          pk.h[0] = (_Float16)b0;
          pk.h[1] = (_Float16)b1;
          pk.h[2] = (_Float16)b2;
          pk.h[3] = (_Float16)b3;
          pk.u = (pk.u & ~0x10001ULL) | tagbits;
          __hip_atomic_store(
              (unsigned long long*)(hnext + (size_t)bg * HH + col), pk.u,
              __ATOMIC_RELAXED, __HIP_MEMORY_SCOPE_AGENT);
          f32x4 ov = {b0, b1, b2, b3};
          *(f32x4*)&out[((size_t)bg * TT + t) * HH + col] = ov;
        }
      }
    }
    __syncthreads();  // (B) all waves' MFMA reads of AshH done

    // ---- stage x(t+1) (consumed after next sync A)
    if (t + 1 < TT && tid < 256) {
      int r = tid >> 5, c = tid & 31;
      AshH[r * 552 + c] =
          (_Float16)x[((size_t)(b0g + r) * TT + (t + 1)) * DD + c];
    }
  }
}

// ---------------------------------------------------------------------------
// Fallback: one launch per timestep (kernel-boundary coherence, fp32 h).
// Only used if the cooperative launch is rejected.
// ---------------------------------------------------------------------------
__global__ __launch_bounds__(256, 2)
void lstm_step(const float* __restrict__ x, const float* __restrict__ Wx,
               const float* __restrict__ Wh, const float* __restrict__ bias,
               float* __restrict__ out, const float* __restrict__ hprev,
               float* __restrict__ hnext, float* __restrict__ cst, int t) {
  __shared__ float Wl[16 * 544];
  __shared__ float Ash[32 * 128];
  __shared__ float Xs[32 * 32];
  __shared__ float Zx[4][32][4];
  __shared__ float BiasS[16];

  const int tid = threadIdx.x;
  const int ks = tid & 7;
  const int btile = (tid >> 3) & 7;
  const int ctile = tid >> 6;
  const int wg = blockIdx.x;
  const int bb = wg & 3;
  const int nb = wg >> 2;
  const int b0g = bb * 32;
  const int n0 = nb * 4;

  for (int idx = tid; idx < 16 * 544; idx += 256) {
    int zc = idx & 15, k = idx >> 4;
    int col = (zc >> 2) * HH + n0 + (zc & 3);
    Wl[zc * 544 + k] = (k < DD) ? Wx[k * G4H + col] : Wh[(k - DD) * G4H + col];
  }
  if (tid < 16) BiasS[tid] = bias[(tid >> 2) * HH + n0 + (tid & 3)];

  {
    int b_l = tid >> 3, kq = tid & 7;
    float4 v = *(const float4*)(x + ((size_t)(b0g + b_l) * TT + t) * DD + kq * 4);
    *(float4*)&Xs[b_l * 32 + kq * 4] = v;
  }

  float acc[4][4];
#pragma unroll
  for (int i = 0; i < 4; ++i)
#pragma unroll
    for (int c = 0; c < 4; ++c) acc[i][c] = 0.f;

  auto mac4 = [&](const float* Abase, int rstride, const float* Wbase) {
    float4 a4[4], w4[4];
#pragma unroll
    for (int i = 0; i < 4; ++i)
      a4[i] = *(const float4*)(Abase + (btile * 4 + i) * rstride);
#pragma unroll
    for (int c = 0; c < 4; ++c) w4[c] = *(const float4*)(Wbase + c * 544);
#pragma unroll
    for (int i = 0; i < 4; ++i)
#pragma unroll
      for (int c = 0; c < 4; ++c)
        acc[i][c] += a4[i].x * w4[c].x + a4[i].y * w4[c].y +
                     a4[i].z * w4[c].z + a4[i].w * w4[c].w;
  };

  for (int ch = 0; ch < 4; ++ch) {
    __syncthreads();
    for (int r = 0; r < 4; ++r) {
      int fidx = r * 256 + tid;
      int b_l = fidx >> 5, kq = fidx & 31;
      float4 v = *(const float4*)(hprev + (size_t)(b0g + b_l) * HH + ch * 128 +
                                  kq * 4);
      *(float4*)&Ash[b_l * 128 + kq * 4] = v;
    }
    __syncthreads();
    if (ch == 0) mac4(&Xs[ks * 4], 32, &Wl[(ctile * 4) * 544 + ks * 4]);
#pragma unroll
    for (int j = 0; j < 4; ++j)
      mac4(&Ash[j * 32 + ks * 4], 128,
           &Wl[(ctile * 4) * 544 + DD + ch * 128 + j * 32 + ks * 4]);
  }

#pragma unroll
  for (int i = 0; i < 4; ++i)
#pragma unroll
    for (int c = 0; c < 4; ++c) {
      float v = acc[i][c];
      v += __shfl_xor(v, 1);
      v += __shfl_xor(v, 2);
      v += __shfl_xor(v, 4);
      acc[i][c] = v;
    }

  if (ks == 0) {
#pragma unroll
    for (int i = 0; i < 4; ++i)
#pragma unroll
      for (int c = 0; c < 4; ++c)
        Zx[ctile][btile * 4 + i][c] = acc[i][c] + BiasS[ctile * 4 + c];
  }
  __syncthreads();

  if (tid < 128) {
    int b_l = tid >> 2, nn = tid & 3;
    float zi = Zx[0][b_l][nn], zf = Zx[1][b_l][nn];
    float zg = Zx[2][b_l][nn], zo = Zx[3][b_l][nn];
    int bg = b0g + b_l, col = n0 + nn;
    size_t cidx = (size_t)bg * HH + col;
    float cnew = sigf(zf) * cst[cidx] + sigf(zi) * tanhf(zg);
    cst[cidx] = cnew;
    float hv = sigf(zo) * tanhf(cnew);
    hnext[cidx] = hv;
    out[((size_t)bg * TT + t) * HH + col] = hv;
  }
}

extern "C" void kernel_launch(void* const* d_in, const int* in_sizes, int n_in,
                              void* d_out, int out_size, void* d_ws, size_t ws_size,
                              hipStream_t stream) {
  const float* x = (const float*)d_in[0];
  const float* Wx = (const float*)d_in[1];
  const float* Wh = (const float*)d_in[2];
  const float* bv = (const float*)d_in[3];
  float* out = (float*)d_out;
  float* hws = (float*)d_ws;

  // zero: buf0 | buf1 | (bar) | cst = (3*65536 + 256) * 4 bytes
  hipMemsetAsync(d_ws, 0, (size_t)(3 * 65536 + 256) * 4, stream);

  void* args[] = {(void*)&x, (void*)&Wx, (void*)&Wh,
                  (void*)&bv, (void*)&out, (void*)&hws};
  hipError_t err = hipLaunchCooperativeKernel(
      reinterpret_cast<void*>(lstm_persistent), dim3(256), dim3(512), args, 0,
      stream);
  if (err != hipSuccess) {
    (void)hipGetLastError();
    float* buf0 = hws;
    float* buf1 = hws + BB * HH;
    float* cst = hws + 2 * BB * HH + 256;
    for (int t = 0; t < TT; ++t) {
      const float* hp = (t & 1) ? buf1 : buf0;
      float* hn = (t & 1) ? buf0 : buf1;
      lstm_step<<<dim3(512), dim3(256), 0, stream>>>(x, Wx, Wh, bv, out, hp, hn,
                                                     cst, t);
    }
  }
}

// Round 10
// 1213.380 us; speedup vs baseline: 1.7702x; 1.7702x over previous
//
#include <hip/hip_runtime.h>
#include <hip/hip_fp16.h>
#include <cmath>

#define BB 128
#define TT 365
#define DD 32
#define HH 512
#define G4H 2048  // 4*HH

// ws layout: buf0 fp16 at byte 0 (131072B used) | buf1 fp16 at byte 262144
//            (bar region unused by v11; kept for fallback/cst)
//            cst at float-ofs 131328 (fallback only, fp32)
// hipMemsetAsync zeroes [0, 787456) bytes each call -> both h buffers zero
// (zero bits == tag 0 + h == 0 == exactly step 0's expected state).

typedef float f32x4 __attribute__((ext_vector_type(4)));
typedef _Float16 f16x8 __attribute__((ext_vector_type(8)));

__device__ __forceinline__ float sigf(float z) { return 1.f / (1.f + __expf(-z)); }

// fast tanh: (1-e)/(1+e) with e=exp(-2|x|), sign restored; e<=1 so no overflow
__device__ __forceinline__ float ftanh(float z) {
  float a = fabsf(z);
  float e = __expf(-2.f * a);
  float r = (1.f - e) / (1.f + e);
  return (z < 0.f) ? -r : r;
}

// ---------------------------------------------------------------------------
// Persistent kernel v11: v8's exact body (1086us, passed: 256 WGs x 512 thr,
// 16 batch groups x 8 rows x 16 col-WGs, W as MFMA B-fragments in VGPRs,
// LDS epilogue, coalesced out + pack-4 h stores) with ONLY the cross-WG
// handshake replaced: TAGGED DATA instead of counter barrier. Each 8B
// h-word (4 fp16) carries a 2-bit step tag ((t+1)&3) in bit0 (fp16[0] lsb)
// and bit16 (fp16[1] lsb); consumers poll their own 2 words until tags
// match t&3 -- the data load IS the discovery. Removes 2 of v8's 4 serial
// fabric RTs per step (store-drain vmcnt(0) + arrive-add + count-poll ->
// just store + tagged load). Atomicity of the 8B word makes tag and data
// inseparable: no ordering ops needed anywhere. Skew safety: producer can
// only reach step t's store after observing ALL step-(t-1) tags, which
// data-depend on every group member's step t-1 stores -> max skew 1 step;
// stale residue in a buffer is always tag t-2 (mod 4) != t. v10 validated
// the tag mechanics (passed); its 2x regression was the uncoalesced out
// store (WRITE 143->280MB), which v11 reverts to v8's coalesced form.
// Syncs/step 3 -> 2. Op class unchanged: agent-scope __hip_atomic_*.
// ---------------------------------------------------------------------------
__global__ __launch_bounds__(512, 2)
void lstm_persistent(const float* __restrict__ x,
                     const float* __restrict__ Wx,
                     const float* __restrict__ Wh,
                     const float* __restrict__ bias,
                     float* __restrict__ out,
                     float* __restrict__ hws) {
  __shared__ __align__(16) _Float16 WlH[128 * 552];  // 141312 B (init staging)
  __shared__ __align__(16) _Float16 AshH[8 * 552];   // 8832 B  [x(32)|h(512)]
  __shared__ __align__(16) float ZxS[8 * 128];       // 4096 B
  __shared__ __align__(16) float Cs[8][32];          // 1024 B
  __shared__ __align__(16) float BiasS[128];         // 512 B
  // total ~155.8 KB -> 1 WG/CU

  const int tid = threadIdx.x;
  const int lane = tid & 63;
  const int wv = tid >> 6;                 // wave id [0,8)
  const int fcol = wv * 16 + (lane & 15);  // output col [0,128)
  const int kq = lane >> 4;                // k-subgroup [0,4)
  const int arow = lane & 15;              // A-fragment row (valid if <8)
  const int wg = blockIdx.x;
  const int bb = wg & 15;                  // batch group [0,16), 8 rows
  const int nb = wg >> 4;                  // col-WG [0,16), 32 h-cols
  const int b0g = bb * 8;
  const int n0 = nb * 32;

  // ---- stage weights as fp16: lanes 0..31 read 32 consecutive cols
  {
    const int cl = tid & 31;
    const int pg = tid >> 5;  // [0,16)
    for (int it = 0; it < 136; ++it) {
      int p = it * 16 + pg;  // [0, 544*4)
      int k = p >> 2, g = p & 3;
      int col = g * HH + n0 + cl;
      float v = (k < DD) ? Wx[k * G4H + col] : Wh[(k - DD) * G4H + col];
      WlH[(g * 32 + cl) * 552 + k] = (_Float16)v;
    }
  }
  if (tid < 128) BiasS[tid] = bias[(tid >> 5) * HH + n0 + (tid & 31)];
  if (tid < 256) Cs[tid >> 5][tid & 31] = 0.f;

  _Float16* hb0 = (_Float16*)hws;  // fp16 h buffers (tagged 8B words)
  _Float16* hb1 = (_Float16*)(hws + BB * HH);

  __syncthreads();  // WlH + BiasS ready

  // ---- hoist this wave's B-fragments into registers (persist 365 steps)
  f16x8 bfrag[17];
#pragma unroll
  for (int kk = 0; kk < 17; ++kk)
    bfrag[kk] = *(const f16x8*)&WlH[fcol * 552 + kk * 32 + kq * 8];
  const float bias_r = BiasS[fcol];

  // ---- per-thread h-word addresses (2 words: idx = r*512+tid)
  const int rr0 = tid >> 7, kk0 = tid & 127;
  const int rr1 = (512 + tid) >> 7, kk1 = (512 + tid) & 127;

  for (int t = 0; t < TT; ++t) {
    const _Float16* hprev = (t & 1) ? hb1 : hb0;
    _Float16* hnext = (t & 1) ? hb0 : hb1;

    // ---- stage x(t) into AshH x-region (prev step's MFMA done at sync B)
    if (tid < 256) {
      int r = tid >> 5, c = tid & 31;
      AshH[r * 552 + c] = (_Float16)x[((size_t)(b0g + r) * TT + t) * DD + c];
    }

    // ---- tagged h loads: poll own 2 words until tag == t&3 (agent-scope).
    //      The data load IS the discovery: no barrier, no counter.
    {
      const unsigned exp_tag = (unsigned)t & 3u;
      const unsigned long long M = 0x0000000000010001ULL;
      const unsigned long long want =
          (unsigned long long)(exp_tag & 1u) |
          ((unsigned long long)((exp_tag >> 1) & 1u) << 16);
      const unsigned long long* a0 =
          (const unsigned long long*)(hprev + (size_t)(b0g + rr0) * HH + kk0 * 4);
      const unsigned long long* a1 =
          (const unsigned long long*)(hprev + (size_t)(b0g + rr1) * HH + kk1 * 4);
      unsigned long long w0 =
          __hip_atomic_load(a0, __ATOMIC_RELAXED, __HIP_MEMORY_SCOPE_AGENT);
      unsigned long long w1 =
          __hip_atomic_load(a1, __ATOMIC_RELAXED, __HIP_MEMORY_SCOPE_AGENT);
      while ((w0 & M) != want)
        w0 = __hip_atomic_load(a0, __ATOMIC_RELAXED, __HIP_MEMORY_SCOPE_AGENT);
      while ((w1 & M) != want)
        w1 = __hip_atomic_load(a1, __ATOMIC_RELAXED, __HIP_MEMORY_SCOPE_AGENT);
      *(unsigned long long*)&AshH[rr0 * 552 + DD + kk0 * 4] = w0;
      *(unsigned long long*)&AshH[rr1 * 552 + DD + kk1 * 4] = w1;
    }
    __syncthreads();  // (A) AshH ready

    // ---- MFMA: Z[16(8 valid) x 16] per wave, K=544, 2 accumulators
    f32x4 acc0 = {bias_r, bias_r, bias_r, bias_r};
    f32x4 acc1 = {0.f, 0.f, 0.f, 0.f};
#pragma unroll
    for (int kk = 0; kk < 17; ++kk) {
      f16x8 af;
      if (arow < 8) {
        af = *(const f16x8*)&AshH[arow * 552 + kk * 32 + kq * 8];
      } else {
        f16x8 z = {};
        af = z;
      }
      if (kk & 1)
        acc1 = __builtin_amdgcn_mfma_f32_16x16x32_f16(af, bfrag[kk], acc1, 0, 0, 0);
      else
        acc0 = __builtin_amdgcn_mfma_f32_16x16x32_f16(af, bfrag[kk], acc0, 0, 0, 0);
    }
    // C/D: col=lane&15 (-> fcol), row=(lane>>4)*4+r; rows 0..7 valid
    if (kq < 2) {
#pragma unroll
      for (int r = 0; r < 4; ++r)
        ZxS[(kq * 4 + r) * 128 + fcol] = acc0[r] + acc1[r];
    }
    __syncthreads();  // (B) ZxS ready; all MFMA reads of AshH done

    if (tid < 256) {
      int b_l = tid >> 5, nn = tid & 31;
      float zi = ZxS[b_l * 128 + nn];
      float zf = ZxS[b_l * 128 + 32 + nn];
      float zg = ZxS[b_l * 128 + 64 + nn];
      float zo = ZxS[b_l * 128 + 96 + nn];
      float cnew = sigf(zf) * Cs[b_l][nn] + sigf(zi) * ftanh(zg);
      Cs[b_l][nn] = cnew;
      float hv = sigf(zo) * ftanh(cnew);
      int bg = b0g + b_l, col = n0 + nn;
      // ---- pack 4 consecutive cols into ONE tagged 8B agent-scope store
      int base = lane & ~3;
      float h0 = __shfl(hv, base + 0);
      float h1 = __shfl(hv, base + 1);
      float h2 = __shfl(hv, base + 2);
      float h3 = __shfl(hv, base + 3);
      if ((lane & 3) == 0) {
        const unsigned ntag = (unsigned)(t + 1) & 3u;
        const unsigned long long tagbits =
            (unsigned long long)(ntag & 1u) |
            ((unsigned long long)((ntag >> 1) & 1u) << 16);
        union { unsigned long long u; _Float16 h[4]; } pk;
        pk.h[0] = (_Float16)h0;
        pk.h[1] = (_Float16)h1;
        pk.h[2] = (_Float16)h2;
        pk.h[3] = (_Float16)h3;
        pk.u = (pk.u & ~0x0000000000010001ULL) | tagbits;
        __hip_atomic_store(
            (unsigned long long*)(hnext + (size_t)bg * HH + col), pk.u,
            __ATOMIC_RELAXED, __HIP_MEMORY_SCOPE_AGENT);
      }
      // ---- coalesced fp32 out store (v8's proven form: 128B per row run)
      out[((size_t)bg * TT + t) * HH + col] = hv;
    }
    // no trailing sync: next iteration's tagged poll gates progress;
    // AshH safe to rewrite (sync B passed), Cs/ZxS touched by same lanes.
  }
}

// ---------------------------------------------------------------------------
// Fallback: one launch per timestep (kernel-boundary coherence, fp32 h).
// Only used if the cooperative launch is rejected.
// ---------------------------------------------------------------------------
__global__ __launch_bounds__(256, 2)
void lstm_step(const float* __restrict__ x, const float* __restrict__ Wx,
               const float* __restrict__ Wh, const float* __restrict__ bias,
               float* __restrict__ out, const float* __restrict__ hprev,
               float* __restrict__ hnext, float* __restrict__ cst, int t) {
  __shared__ float Wl[16 * 544];
  __shared__ float Ash[32 * 128];
  __shared__ float Xs[32 * 32];
  __shared__ float Zx[4][32][4];
  __shared__ float BiasS[16];

  const int tid = threadIdx.x;
  const int ks = tid & 7;
  const int btile = (tid >> 3) & 7;
  const int ctile = tid >> 6;
  const int wg = blockIdx.x;
  const int bb = wg & 3;
  const int nb = wg >> 2;
  const int b0g = bb * 32;
  const int n0 = nb * 4;

  for (int idx = tid; idx < 16 * 544; idx += 256) {
    int zc = idx & 15, k = idx >> 4;
    int col = (zc >> 2) * HH + n0 + (zc & 3);
    Wl[zc * 544 + k] = (k < DD) ? Wx[k * G4H + col] : Wh[(k - DD) * G4H + col];
  }
  if (tid < 16) BiasS[tid] = bias[(tid >> 2) * HH + n0 + (tid & 3)];

  {
    int b_l = tid >> 3, kq = tid & 7;
    float4 v = *(const float4*)(x + ((size_t)(b0g + b_l) * TT + t) * DD + kq * 4);
    *(float4*)&Xs[b_l * 32 + kq * 4] = v;
  }

  float acc[4][4];
#pragma unroll
  for (int i = 0; i < 4; ++i)
#pragma unroll
    for (int c = 0; c < 4; ++c) acc[i][c] = 0.f;

  auto mac4 = [&](const float* Abase, int rstride, const float* Wbase) {
    float4 a4[4], w4[4];
#pragma unroll
    for (int i = 0; i < 4; ++i)
      a4[i] = *(const float4*)(Abase + (btile * 4 + i) * rstride);
#pragma unroll
    for (int c = 0; c < 4; ++c) w4[c] = *(const float4*)(Wbase + c * 544);
#pragma unroll
    for (int i = 0; i < 4; ++i)
#pragma unroll
      for (int c = 0; c < 4; ++c)
        acc[i][c] += a4[i].x * w4[c].x + a4[i].y * w4[c].y +
                     a4[i].z * w4[c].z + a4[i].w * w4[c].w;
  };

  for (int ch = 0; ch < 4; ++ch) {
    __syncthreads();
    for (int r = 0; r < 4; ++r) {
      int fidx = r * 256 + tid;
      int b_l = fidx >> 5, kq = fidx & 31;
      float4 v = *(const float4*)(hprev + (size_t)(b0g + b_l) * HH + ch * 128 +
                                  kq * 4);
      *(float4*)&Ash[b_l * 128 + kq * 4] = v;
    }
    __syncthreads();
    if (ch == 0) mac4(&Xs[ks * 4], 32, &Wl[(ctile * 4) * 544 + ks * 4]);
#pragma unroll
    for (int j = 0; j < 4; ++j)
      mac4(&Ash[j * 32 + ks * 4], 128,
           &Wl[(ctile * 4) * 544 + DD + ch * 128 + j * 32 + ks * 4]);
  }

#pragma unroll
  for (int i = 0; i < 4; ++i)
#pragma unroll
    for (int c = 0; c < 4; ++c) {
      float v = acc[i][c];
      v += __shfl_xor(v, 1);
      v += __shfl_xor(v, 2);
      v += __shfl_xor(v, 4);
      acc[i][c] = v;
    }

  if (ks == 0) {
#pragma unroll
    for (int i = 0; i < 4; ++i)
#pragma unroll
      for (int c = 0; c < 4; ++c)
        Zx[ctile][btile * 4 + i][c] = acc[i][c] + BiasS[ctile * 4 + c];
  }
  __syncthreads();

  if (tid < 128) {
    int b_l = tid >> 2, nn = tid & 3;
    float zi = Zx[0][b_l][nn], zf = Zx[1][b_l][nn];
    float zg = Zx[2][b_l][nn], zo = Zx[3][b_l][nn];
    int bg = b0g + b_l, col = n0 + nn;
    size_t cidx = (size_t)bg * HH + col;
    float cnew = sigf(zf) * cst[cidx] + sigf(zi) * tanhf(zg);
    cst[cidx] = cnew;
    float hv = sigf(zo) * tanhf(cnew);
    hnext[cidx] = hv;
    out[((size_t)bg * TT + t) * HH + col] = hv;
  }
}

extern "C" void kernel_launch(void* const* d_in, const int* in_sizes, int n_in,
                              void* d_out, int out_size, void* d_ws, size_t ws_size,
                              hipStream_t stream) {
  const float* x = (const float*)d_in[0];
  const float* Wx = (const float*)d_in[1];
  const float* Wh = (const float*)d_in[2];
  const float* bv = (const float*)d_in[3];
  float* out = (float*)d_out;
  float* hws = (float*)d_ws;

  // zero: buf0 | buf1 | (bar) | cst = (3*65536 + 256) * 4 bytes
  hipMemsetAsync(d_ws, 0, (size_t)(3 * 65536 + 256) * 4, stream);

  void* args[] = {(void*)&x, (void*)&Wx, (void*)&Wh,
                  (void*)&bv, (void*)&out, (void*)&hws};
  hipError_t err = hipLaunchCooperativeKernel(
      reinterpret_cast<void*>(lstm_persistent), dim3(256), dim3(512), args, 0,
      stream);
  if (err != hipSuccess) {
    (void)hipGetLastError();
    float* buf0 = hws;
    float* buf1 = hws + BB * HH;
    float* cst = hws + 2 * BB * HH + 256;
    for (int t = 0; t < TT; ++t) {
      const float* hp = (t & 1) ? buf1 : buf0;
      float* hn = (t & 1) ? buf0 : buf1;
      lstm_step<<<dim3(512), dim3(256), 0, stream>>>(x, Wx, Wh, bv, out, hp, hn,
                                                     cst, t);
    }
  }
}

// Round 12
// 1135.812 us; speedup vs baseline: 1.8911x; 1.0683x over previous
//
#include <hip/hip_runtime.h>
#include <hip/hip_fp16.h>
#include <cmath>

#define BB 128
#define TT 365
#define DD 32
#define HH 512
#define G4H 2048  // 4*HH

// ws layout: buf0 fp16 at byte 0 (131072B used) | buf1 fp16 at byte 262144
//            bar at byte 524288 (32 groups x 8 uints = 256 uints)
//            cst at float-ofs 131328 (fallback only, fp32)
// hipMemsetAsync zeroes [0, 787456) bytes each call (h buffers zero == h0).

typedef float f32x4 __attribute__((ext_vector_type(4)));
typedef _Float16 f16x8 __attribute__((ext_vector_type(8)));

__device__ __forceinline__ float sigf(float z) { return 1.f / (1.f + __expf(-z)); }

// fast tanh: (1-e)/(1+e) with e=exp(-2|x|), sign restored; e<=1 so no overflow
__device__ __forceinline__ float ftanh(float z) {
  float a = fabsf(z);
  float e = __expf(-2.f * a);
  float r = (1.f - e) / (1.f + e);
  return (z < 0.f) ? -r : r;
}

// ---------------------------------------------------------------------------
// Persistent kernel v13 == v12 with its LDS race fixed: v12 read bias0/bias1
// from BiasS BEFORE the __syncthreads() covering the tid<256 writes -- waves
// 4..7 read uninitialized LDS and even wave 0 read wave 2's slot. Losing the
// forget-gate's +1.0 unit bias explains the measured absmax 0.818. v13 moves
// the sync before the read; everything else is v12 verbatim:
// 256 WGs x 512 thr as 32 batch groups x 4 rows x 8 col-WGs x 256 gate-cols.
// Halves the atomic-op floor seen across v8/v9/v11 (~3us/step independent of
// handshake): h-loads 262K -> 131K/step (1 agent-scope 8B load per thread).
// Each wave holds 2 MFMA B-tiles (136 VGPRs, 365 steps) staged in 2 passes
// through one 128x552 LDS buffer; one A-read feeds both MFMAs. v8's proven
// counter barrier (8 arrivals/group). Out store nontemporal. Coherence op
// classes unchanged (v2/v6/v8-proven agent-scope atomics).
// ---------------------------------------------------------------------------
__global__ __launch_bounds__(512, 2)
void lstm_persistent(const float* __restrict__ x,
                     const float* __restrict__ Wx,
                     const float* __restrict__ Wh,
                     const float* __restrict__ bias,
                     float* __restrict__ out,
                     float* __restrict__ hws) {
  __shared__ __align__(16) _Float16 WlH[128 * 552];  // 141312 B (init staging, 2 passes)
  __shared__ __align__(16) _Float16 AshH[4 * 552];   // 4416 B  [x(32)|h(512)]
  __shared__ __align__(16) float ZxS[4 * 256];       // 4096 B
  __shared__ __align__(16) float Cs[4][64];          // 1024 B
  __shared__ __align__(16) float BiasS[256];         // 1024 B
  // total ~151.6 KB -> 1 WG/CU

  const int tid = threadIdx.x;
  const int lane = tid & 63;
  const int wv = tid >> 6;                 // wave id [0,8)
  const int kq = lane >> 4;                // k-subgroup [0,4)
  const int arow = lane & 15;              // A-fragment row (valid if <4)
  const int wg = blockIdx.x;
  const int bb = wg & 31;                  // batch group [0,32), 4 rows
  const int nb = wg >> 5;                  // col-WG [0,8), 64 h-cols
  const int b0g = bb * 4;
  const int n0 = nb * 64;
  const int lc0 = wv * 16 + (lane & 15);   // local col within a 128-col pass

  _Float16* hb0 = (_Float16*)hws;  // fp16 h buffers (packed 4/word)
  _Float16* hb1 = (_Float16*)(hws + BB * HH);
  unsigned int* bar = (unsigned int*)(hws + 2 * BB * HH) + bb * 8;

  // ---- stage weights in 2 passes of 128 local cols; hoist B-frags to VGPRs
  f16x8 bfrag0[17], bfrag1[17];
#pragma unroll 1
  for (int p = 0; p < 2; ++p) {
    // local col lc = g_loc*64 + cl  (gate g = p*2+g_loc), k in [0,544)
    const int cl = tid & 63;
    const int pg = tid >> 6;  // [0,8)
    for (int it = 0; it < 136; ++it) {
      int pr = it * 8 + pg;  // [0, 1088): (k, g_loc) pairs
      int k = pr >> 1, g_loc = pr & 1;
      int g = p * 2 + g_loc;
      int col = g * HH + n0 + cl;
      float v = (k < DD) ? Wx[k * G4H + col] : Wh[(k - DD) * G4H + col];
      WlH[(g_loc * 64 + cl) * 552 + k] = (_Float16)v;
    }
    __syncthreads();  // pass p staged
    if (p == 0) {
#pragma unroll
      for (int kk = 0; kk < 17; ++kk)
        bfrag0[kk] = *(const f16x8*)&WlH[lc0 * 552 + kk * 32 + kq * 8];
    } else {
#pragma unroll
      for (int kk = 0; kk < 17; ++kk)
        bfrag1[kk] = *(const f16x8*)&WlH[lc0 * 552 + kk * 32 + kq * 8];
    }
    __syncthreads();  // frags read; WlH free for next pass
  }
  if (tid < 256) {
    BiasS[tid] = bias[(tid >> 6) * HH + n0 + (tid & 63)];
    Cs[tid >> 6][tid & 63] = 0.f;
  }
  __syncthreads();  // BiasS/Cs visible to ALL waves (v12's missing sync)
  const float bias0 = BiasS[lc0];        // gates i|f  (lc0 in [0,128))
  const float bias1 = BiasS[128 + lc0];  // gates g|o

  // ---- per-thread h-word address (1 word: 512 words per WG, 512 threads)
  const int rr0 = tid >> 7, kk0 = tid & 127;  // row [0,4), word [0,128)

  for (int t = 0; t < TT; ++t) {
    const _Float16* hprev = (t & 1) ? hb1 : hb0;
    _Float16* hnext = (t & 1) ? hb0 : hb1;

    // ---- stage x(t) into AshH x-region
    if (tid < 128) {
      int r = tid >> 5, c = tid & 31;
      AshH[r * 552 + c] = (_Float16)x[((size_t)(b0g + r) * TT + t) * DD + c];
    }
    // ---- h load: ONE agent-scope 8B atomic load per thread (proven class)
    {
      unsigned long long w0 = __hip_atomic_load(
          (const unsigned long long*)(hprev + (size_t)(b0g + rr0) * HH + kk0 * 4),
          __ATOMIC_RELAXED, __HIP_MEMORY_SCOPE_AGENT);
      *(unsigned long long*)&AshH[rr0 * 552 + DD + kk0 * 4] = w0;
    }
    __syncthreads();  // (A) AshH ready

    // ---- MFMA: two 16-col tiles per wave, K=544; one A-read feeds both
    f32x4 a00 = {bias0, bias0, bias0, bias0};
    f32x4 a01 = {0.f, 0.f, 0.f, 0.f};
    f32x4 a10 = {bias1, bias1, bias1, bias1};
    f32x4 a11 = {0.f, 0.f, 0.f, 0.f};
#pragma unroll
    for (int kk = 0; kk < 17; ++kk) {
      f16x8 af;
      if (arow < 4) {
        af = *(const f16x8*)&AshH[arow * 552 + kk * 32 + kq * 8];
      } else {
        f16x8 z = {};
        af = z;
      }
      if (kk & 1) {
        a01 = __builtin_amdgcn_mfma_f32_16x16x32_f16(af, bfrag0[kk], a01, 0, 0, 0);
        a11 = __builtin_amdgcn_mfma_f32_16x16x32_f16(af, bfrag1[kk], a11, 0, 0, 0);
      } else {
        a00 = __builtin_amdgcn_mfma_f32_16x16x32_f16(af, bfrag0[kk], a00, 0, 0, 0);
        a10 = __builtin_amdgcn_mfma_f32_16x16x32_f16(af, bfrag1[kk], a10, 0, 0, 0);
      }
    }
    // C/D: col=lane&15, row=(lane>>4)*4+r -> rows 0..3 live in kq==0 lanes
    if (kq == 0) {
#pragma unroll
      for (int r = 0; r < 4; ++r) {
        ZxS[r * 256 + lc0] = a00[r] + a01[r];
        ZxS[r * 256 + 128 + lc0] = a10[r] + a11[r];
      }
    }
    __syncthreads();  // (B) ZxS ready; all MFMA reads of AshH done

    if (tid < 256) {
      int b_l = tid >> 6, nn = tid & 63;  // row, h-col; wave == row
      float zi = ZxS[b_l * 256 + nn];
      float zf = ZxS[b_l * 256 + 64 + nn];
      float zg = ZxS[b_l * 256 + 128 + nn];
      float zo = ZxS[b_l * 256 + 192 + nn];
      float cnew = sigf(zf) * Cs[b_l][nn] + sigf(zi) * ftanh(zg);
      Cs[b_l][nn] = cnew;
      float hv = sigf(zo) * ftanh(cnew);
      int bg = b0g + b_l, col = n0 + nn;
      // ---- pack 4 consecutive cols into ONE 8B agent-scope atomic store
      int base = lane & ~3;
      float h0 = __shfl(hv, base + 0);
      float h1 = __shfl(hv, base + 1);
      float h2 = __shfl(hv, base + 2);
      float h3 = __shfl(hv, base + 3);
      if ((lane & 3) == 0) {
        union { unsigned long long u; _Float16 h[4]; } pk;
        pk.h[0] = (_Float16)h0;
        pk.h[1] = (_Float16)h1;
        pk.h[2] = (_Float16)h2;
        pk.h[3] = (_Float16)h3;
        __hip_atomic_store(
            (unsigned long long*)(hnext + (size_t)bg * HH + col), pk.u,
            __ATOMIC_RELAXED, __HIP_MEMORY_SCOPE_AGENT);
      }
      // ---- coalesced nontemporal fp32 out store (256B per row segment)
      __builtin_nontemporal_store(hv, &out[((size_t)bg * TT + t) * HH + col]);
    }
    __syncthreads();  // drains vmcnt(0): h stores at coherence point

    // per-group barrier (8 WGs): v8's exact proven agent-scope barrier
    if (tid == 0) {
      __hip_atomic_fetch_add(bar, 1u, __ATOMIC_RELAXED,
                             __HIP_MEMORY_SCOPE_AGENT);
      unsigned int target = 8u * (unsigned)(t + 1);
      while (__hip_atomic_load(bar, __ATOMIC_RELAXED,
                               __HIP_MEMORY_SCOPE_AGENT) < target) {
      }
    }
    __syncthreads();
  }
}

// ---------------------------------------------------------------------------
// Fallback: one launch per timestep (kernel-boundary coherence, fp32 h).
// Only used if the cooperative launch is rejected.
// ---------------------------------------------------------------------------
__global__ __launch_bounds__(256, 2)
void lstm_step(const float* __restrict__ x, const float* __restrict__ Wx,
               const float* __restrict__ Wh, const float* __restrict__ bias,
               float* __restrict__ out, const float* __restrict__ hprev,
               float* __restrict__ hnext, float* __restrict__ cst, int t) {
  __shared__ float Wl[16 * 544];
  __shared__ float Ash[32 * 128];
  __shared__ float Xs[32 * 32];
  __shared__ float Zx[4][32][4];
  __shared__ float BiasS[16];

  const int tid = threadIdx.x;
  const int ks = tid & 7;
  const int btile = (tid >> 3) & 7;
  const int ctile = tid >> 6;
  const int wg = blockIdx.x;
  const int bb = wg & 3;
  const int nb = wg >> 2;
  const int b0g = bb * 32;
  const int n0 = nb * 4;

  for (int idx = tid; idx < 16 * 544; idx += 256) {
    int zc = idx & 15, k = idx >> 4;
    int col = (zc >> 2) * HH + n0 + (zc & 3);
    Wl[zc * 544 + k] = (k < DD) ? Wx[k * G4H + col] : Wh[(k - DD) * G4H + col];
  }
  if (tid < 16) BiasS[tid] = bias[(tid >> 2) * HH + n0 + (tid & 3)];

  {
    int b_l = tid >> 3, kq = tid & 7;
    float4 v = *(const float4*)(x + ((size_t)(b0g + b_l) * TT + t) * DD + kq * 4);
    *(float4*)&Xs[b_l * 32 + kq * 4] = v;
  }

  float acc[4][4];
#pragma unroll
  for (int i = 0; i < 4; ++i)
#pragma unroll
    for (int c = 0; c < 4; ++c) acc[i][c] = 0.f;

  auto mac4 = [&](const float* Abase, int rstride, const float* Wbase) {
    float4 a4[4], w4[4];
#pragma unroll
    for (int i = 0; i < 4; ++i)
      a4[i] = *(const float4*)(Abase + (btile * 4 + i) * rstride);
#pragma unroll
    for (int c = 0; c < 4; ++c) w4[c] = *(const float4*)(Wbase + c * 544);
#pragma unroll
    for (int i = 0; i < 4; ++i)
#pragma unroll
      for (int c = 0; c < 4; ++c)
        acc[i][c] += a4[i].x * w4[c].x + a4[i].y * w4[c].y +
                     a4[i].z * w4[c].z + a4[i].w * w4[c].w;
  };

  for (int ch = 0; ch < 4; ++ch) {
    __syncthreads();
    for (int r = 0; r < 4; ++r) {
      int fidx = r * 256 + tid;
      int b_l = fidx >> 5, kq = fidx & 31;
      float4 v = *(const float4*)(hprev + (size_t)(b0g + b_l) * HH + ch * 128 +
                                  kq * 4);
      *(float4*)&Ash[b_l * 128 + kq * 4] = v;
    }
    __syncthreads();
    if (ch == 0) mac4(&Xs[ks * 4], 32, &Wl[(ctile * 4) * 544 + ks * 4]);
#pragma unroll
    for (int j = 0; j < 4; ++j)
      mac4(&Ash[j * 32 + ks * 4], 128,
           &Wl[(ctile * 4) * 544 + DD + ch * 128 + j * 32 + ks * 4]);
  }

#pragma unroll
  for (int i = 0; i < 4; ++i)
#pragma unroll
    for (int c = 0; c < 4; ++c) {
      float v = acc[i][c];
      v += __shfl_xor(v, 1);
      v += __shfl_xor(v, 2);
      v += __shfl_xor(v, 4);
      acc[i][c] = v;
    }

  if (ks == 0) {
#pragma unroll
    for (int i = 0; i < 4; ++i)
#pragma unroll
      for (int c = 0; c < 4; ++c)
        Zx[ctile][btile * 4 + i][c] = acc[i][c] + BiasS[ctile * 4 + c];
  }
  __syncthreads();

  if (tid < 128) {
    int b_l = tid >> 2, nn = tid & 3;
    float zi = Zx[0][b_l][nn], zf = Zx[1][b_l][nn];
    float zg = Zx[2][b_l][nn], zo = Zx[3][b_l][nn];
    int bg = b0g + b_l, col = n0 + nn;
    size_t cidx = (size_t)bg * HH + col;
    float cnew = sigf(zf) * cst[cidx] + sigf(zi) * tanhf(zg);
    cst[cidx] = cnew;
    float hv = sigf(zo) * tanhf(cnew);
    hnext[cidx] = hv;
    out[((size_t)bg * TT + t) * HH + col] = hv;
  }
}

extern "C" void kernel_launch(void* const* d_in, const int* in_sizes, int n_in,
                              void* d_out, int out_size, void* d_ws, size_t ws_size,
                              hipStream_t stream) {
  const float* x = (const float*)d_in[0];
  const float* Wx = (const float*)d_in[1];
  const float* Wh = (const float*)d_in[2];
  const float* bv = (const float*)d_in[3];
  float* out = (float*)d_out;
  float* hws = (float*)d_ws;

  // zero: buf0 | buf1 | barrier counters | cst = (3*65536 + 256) * 4 bytes
  hipMemsetAsync(d_ws, 0, (size_t)(3 * 65536 + 256) * 4, stream);

  void* args[] = {(void*)&x, (void*)&Wx, (void*)&Wh,
                  (void*)&bv, (void*)&out, (void*)&hws};
  hipError_t err = hipLaunchCooperativeKernel(
      reinterpret_cast<void*>(lstm_persistent), dim3(256), dim3(512), args, 0,
      stream);
  if (err != hipSuccess) {
    (void)hipGetLastError();
    float* buf0 = hws;
    float* buf1 = hws + BB * HH;
    float* cst = hws + 2 * BB * HH + 256;
    for (int t = 0; t < TT; ++t) {
      const float* hp = (t & 1) ? buf1 : buf0;
      float* hn = (t & 1) ? buf0 : buf1;
      lstm_step<<<dim3(512), dim3(256), 0, stream>>>(x, Wx, Wh, bv, out, hp, hn,
                                                     cst, t);
    }
  }
}